// Round 6
// baseline (18092.781 us; speedup 1.0000x reference)
//
#include <hip/hip_runtime.h>
#include <hip/hip_bf16.h>
#include <math.h>

#define NODES 73728   // B*T*N = 128*64*9
#define BB    128
#define TT    64
#define NN    9
#define E_REAL 203648.0f
#define NARR  33

typedef __hip_bfloat16 bf16;

__device__ __forceinline__ float bfdec(unsigned short u) {
  return __uint_as_float(((unsigned)u) << 16);
}
__device__ __forceinline__ float ldbf1(const bf16* p) {
  return bfdec(*(const unsigned short*)p);
}

// ---------------- dtype detector: low u16 of each fp32 is random mantissa bits ----------------
__global__ __launch_bounds__(256) void detect_kernel(const unsigned short* __restrict__ raw,
                                                     float* __restrict__ flag) {
  __shared__ float sm[256];
  float mx = 0.f;
  for (int i = threadIdx.x; i < 2048; i += 256) mx = fmaxf(mx, fabsf(bfdec(raw[2 * i])));
  sm[threadIdx.x] = mx;
  __syncthreads();
  for (int s = 128; s > 0; s >>= 1) {
    if (threadIdx.x < s) sm[threadIdx.x] = fmaxf(sm[threadIdx.x], sm[threadIdx.x + s]);
    __syncthreads();
  }
  if (threadIdx.x == 0) flag[0] = (sm[0] > 1000.f) ? 1.f : 0.f;
}

// ---------------- convert all inputs to fp32 params region ----------------
struct CvtArgs { const void* src[NARR]; int size[NARR]; int off[NARR]; };

__global__ __launch_bounds__(256) void convert_kernel(CvtArgs a, const float* __restrict__ flag,
                                                      float* __restrict__ dst) {
  int i = blockIdx.y;
  int sz = a.size[i];
  bool isf32 = flag[0] > 0.5f;
  const float* sf = (const float*)a.src[i];
  const unsigned short* sh = (const unsigned short*)a.src[i];
  float* d = dst + a.off[i];
  for (int j = blockIdx.x * 256 + threadIdx.x; j < sz; j += gridDim.x * 256)
    d[j] = isf32 ? sf[j] : bfdec(sh[j]);
}

// ---------------- encoder: one block per node, thread d in 0..127 ----------------
__global__ __launch_bounds__(128) void encoder_simple(const float* __restrict__ nf,
    const float* __restrict__ encW, const float* __restrict__ encb, float* __restrict__ X) {
  int v = blockIdx.x;
  int d = threadIdx.x;
  int n = v % NN;
  float f[14];
#pragma unroll
  for (int i = 0; i < 10; i++) f[i] = nf[(size_t)v * 10 + i];
  f[10] = (n < 7) ? 1.f : 0.f;
  f[11] = (n == 7) ? 1.f : 0.f;
  f[12] = (n == 8) ? 1.f : 0.f;
  f[13] = fabsf((float)(n - 7));
  const float* w = &encW[((size_t)n * 128 + d) * 14];
  float s = encb[n * 128 + d];
#pragma unroll
  for (int i = 0; i < 14; i++) s = fmaf(f[i], w[i], s);
  X[(size_t)v * 256 + d] = s;
}

// ---------------- fill: spatial edges cancel; temporal telescopes to t=63 minus t=0 ----------------
__global__ __launch_bounds__(256) void fill_kernel(const float* __restrict__ nf,
                                                   float* __restrict__ fill) {
  __shared__ float sx[256], sy[256], sz[256];
  int tid = threadIdx.x;
  float ax = 0.f, ay = 0.f, az = 0.f;
  for (int p = tid; p < BB * NN; p += 256) {
    int b = p / NN, n = p - b * NN;
    size_t late  = (((size_t)b * TT + (TT - 1)) * NN + n) * 10;
    size_t early = (((size_t)b * TT) * NN + n) * 10;
    ax += nf[late + 0] - nf[early + 0];
    ay += nf[late + 1] - nf[early + 1];
    az += nf[late + 2] - nf[early + 2];
  }
  sx[tid] = ax; sy[tid] = ay; sz[tid] = az;
  __syncthreads();
  for (int s = 128; s > 0; s >>= 1) {
    if (tid < s) { sx[tid] += sx[tid + s]; sy[tid] += sy[tid + s]; sz[tid] += sz[tid + s]; }
    __syncthreads();
  }
  if (tid == 0) { fill[0] = sx[0] / E_REAL; fill[1] = sy[0] / E_REAL; fill[2] = sz[0] / E_REAL; }
}

// ---------------- XL[v,c] = sum_k X[v,k]*lW[c,k] + lb[c]  (one block per node) ----------------
__global__ __launch_bounds__(256) void xl_simple(const float* __restrict__ X, int K,
    const float* __restrict__ W, const float* __restrict__ bias, bf16* __restrict__ XL) {
  __shared__ float xrow[256];
  int v = blockIdx.x, c = threadIdx.x;
  if (c < K) xrow[c] = X[(size_t)v * 256 + c];
  __syncthreads();
  const float* wr = &W[(size_t)c * K];
  float s = bias[c];
  for (int k = 0; k < K; k++) s = fmaf(xrow[k], wr[k], s);
  XL[(size_t)v * 256 + c] = __float2bfloat16(s);
}

// ---------------- logits: XR row in-block, 4 edges, per-head softmax -> wbuf[v][h][e] ----------------
__global__ __launch_bounds__(256) void logits_simple(const float* __restrict__ X, int K,
    const float* __restrict__ rW, const float* __restrict__ rb,
    const bf16* __restrict__ XL, const float* __restrict__ nf, const float* __restrict__ fill,
    const float* __restrict__ att, const float* __restrict__ eW, float* __restrict__ wbuf) {
  __shared__ float xrow[256];
  __shared__ float sm[256];
  __shared__ float lg[4][4];
  int v = blockIdx.x, c = threadIdx.x;
  int n = v % NN, t = (v / NN) & 63;
  if (c < K) xrow[c] = X[(size_t)v * 256 + c];
  __syncthreads();
  const float* wr = &rW[(size_t)c * K];
  float xr = rb[c];
  for (int k = 0; k < K; k++) xr = fmaf(xrow[k], wr[k], xr);

  float av = att[c];
  float e0 = eW[c * 3 + 0], e1 = eW[c * 3 + 1], e2 = eW[c * 3 + 2];
  float px = nf[(size_t)v * 10 + 0], py = nf[(size_t)v * 10 + 1], pz = nf[(size_t)v * 10 + 2];
  int  srcs[4]  = { v, v - 1, v + 1, v - NN };
  bool valid[4] = { true, n > 0, n < NN - 1, t > 0 };
#pragma unroll
  for (int e = 0; e < 4; e++) {
    int s = valid[e] ? srcs[e] : v;
    float a0, a1, a2;
    if (e == 0) { a0 = fill[0]; a1 = fill[1]; a2 = fill[2]; }
    else {
      a0 = px - nf[(size_t)s * 10 + 0];
      a1 = py - nf[(size_t)s * 10 + 1];
      a2 = pz - nf[(size_t)s * 10 + 2];
    }
    float xl = ldbf1(&XL[(size_t)s * 256 + c]);
    float m = xl + xr + fmaf(e0, a0, fmaf(e1, a1, e2 * a2));
    m = (m > 0.f) ? m : 0.2f * m;          // leaky_relu 0.2
    sm[c] = m * av;
    __syncthreads();
    if (c < 4) {                            // head c sums its 64 channels serially
      float ssum = 0.f;
      for (int j = 0; j < 64; j++) ssum += sm[c * 64 + j];
      lg[c][e] = valid[e] ? ssum : -1e30f;
    }
    __syncthreads();
  }
  if (c < 4) {
    float mx = fmaxf(fmaxf(lg[c][0], lg[c][1]), fmaxf(lg[c][2], lg[c][3]));
    float wv[4], wsum = 0.f;
#pragma unroll
    for (int e = 0; e < 4; e++) { wv[e] = __expf(lg[c][e] - mx); wsum += wv[e]; }
    float inv = 1.f / wsum;
#pragma unroll
    for (int e = 0; e < 4; e++) wbuf[(size_t)v * 16 + c * 4 + e] = wv[e] * inv;
  }
}

// ---------------- out: xs row in-block + aggregate + LayerNorm + SiLU, in-place on X ----------------
__global__ __launch_bounds__(256) void out_simple(float* X, int K,
    const float* __restrict__ sW, const float* __restrict__ bias,
    const bf16* __restrict__ XL, const float* __restrict__ wbuf,
    const float* __restrict__ g, const float* __restrict__ b) {
  __shared__ float xrow[256];
  __shared__ float red[256];
  int v = blockIdx.x, c = threadIdx.x;
  int n = v % NN, t = (v / NN) & 63;
  if (c < K) xrow[c] = X[(size_t)v * 256 + c];   // staged before any write to row v
  __syncthreads();
  const float* wr = &sW[(size_t)c * K];
  float s = bias[c];
  for (int k = 0; k < K; k++) s = fmaf(xrow[k], wr[k], s);

  int  srcs[4]  = { v, v - 1, v + 1, v - NN };
  bool valid[4] = { true, n > 0, n < NN - 1, t > 0 };
  int h = c >> 6;
#pragma unroll
  for (int e = 0; e < 4; e++) {
    int sc = valid[e] ? srcs[e] : v;            // invalid slot has weight exactly 0
    float w = wbuf[(size_t)v * 16 + h * 4 + e];
    s = fmaf(w, ldbf1(&XL[(size_t)sc * 256 + c]), s);
  }
  // LayerNorm over 256 channels
  red[c] = s; __syncthreads();
  for (int st = 128; st > 0; st >>= 1) { if (c < st) red[c] += red[c + st]; __syncthreads(); }
  float mu = red[0] * (1.f / 256.f);
  __syncthreads();
  float d0 = s - mu;
  red[c] = d0 * d0; __syncthreads();
  for (int st = 128; st > 0; st >>= 1) { if (c < st) red[c] += red[c + st]; __syncthreads(); }
  float var = red[0] * (1.f / 256.f);
  float y = d0 * rsqrtf(var + 1e-5f) * g[c] + b[c];
  X[(size_t)v * 256 + c] = y * (1.f / (1.f + __expf(-y)));   // SiLU
}

// ---------------- mean over T*N=576 positions -> (B, 256) FP32 (reference output dtype) ----------------
__global__ __launch_bounds__(256) void pool_kernel(const float* __restrict__ X,
                                                   float* __restrict__ out) {
  int b = blockIdx.x, c = threadIdx.x;
  const float* p = &X[(size_t)b * 576 * 256 + c];
  float s = 0.f;
  for (int i = 0; i < 576; i++) s += p[(size_t)i * 256];
  out[b * 256 + c] = s * (1.f / 576.f);
}

extern "C" void kernel_launch(void* const* d_in, const int* in_sizes, int n_in,
                              void* d_out, int out_size, void* d_ws, size_t ws_size,
                              hipStream_t stream) {
  static const int kSize[NARR] = {
    737280, 16128, 1152,
    32768, 256, 32768, 256, 256, 768, 32768, 256, 256, 256,   // layer 0 (K=128)
    65536, 256, 65536, 256, 256, 768, 65536, 256, 256, 256,   // layer 1 (K=256)
    65536, 256, 65536, 256, 256, 768, 65536, 256, 256, 256    // layer 2 (K=256)
  };
  if (n_in != NARR || out_size != BB * 256) return;
  for (int i = 0; i < NARR; i++) if (in_sizes[i] != kSize[i]) return;

  CvtArgs ca;
  int off = 0;
  for (int i = 0; i < NARR; i++) { ca.src[i] = d_in[i]; ca.size[i] = kSize[i]; ca.off[i] = off; off += kSize[i]; }
  const int PRM_ELEMS = off;   // 1,252,992

  const size_t OFF_FLAG = 0;
  const size_t OFF_FILL = 16;
  const size_t OFF_PRM  = 256;
  const size_t OFF_WB   = OFF_PRM + (size_t)PRM_ELEMS * 4;
  const size_t OFF_XL   = OFF_WB + (size_t)NODES * 16 * 4;
  const size_t OFF_X    = OFF_XL + (size_t)NODES * 256 * 2;    // XL bf16
  const size_t NEED     = OFF_X + (size_t)NODES * 256 * 4;     // ~117.3 MiB (proven fit)
  if (ws_size < NEED) return;

  char* ws = (char*)d_ws;
  float* flag = (float*)(ws + OFF_FLAG);
  float* fill = (float*)(ws + OFF_FILL);
  float* prm  = (float*)(ws + OFF_PRM);
  float* wbuf = (float*)(ws + OFF_WB);
  bf16*  XL   = (bf16*)(ws + OFF_XL);
  float* X    = (float*)(ws + OFF_X);

  detect_kernel<<<1, 256, 0, stream>>>((const unsigned short*)d_in[0], flag);
  convert_kernel<<<dim3(360, NARR), 256, 0, stream>>>(ca, flag, prm);

  const float* nf   = prm + ca.off[0];
  const float* encW = prm + ca.off[1];
  const float* encb = prm + ca.off[2];

  encoder_simple<<<NODES, 128, 0, stream>>>(nf, encW, encb, X);
  fill_kernel<<<1, 256, 0, stream>>>(nf, fill);

  int K = 128;
  for (int L = 0; L < 3; L++) {
    const float* lW   = prm + ca.off[3 + L * 10 + 0];
    const float* lb   = prm + ca.off[3 + L * 10 + 1];
    const float* rW   = prm + ca.off[3 + L * 10 + 2];
    const float* rb   = prm + ca.off[3 + L * 10 + 3];
    const float* att  = prm + ca.off[3 + L * 10 + 4];
    const float* eW   = prm + ca.off[3 + L * 10 + 5];
    const float* sW   = prm + ca.off[3 + L * 10 + 6];
    const float* bias = prm + ca.off[3 + L * 10 + 7];
    const float* g    = prm + ca.off[3 + L * 10 + 8];
    const float* b    = prm + ca.off[3 + L * 10 + 9];
    xl_simple<<<NODES, 256, 0, stream>>>(X, K, lW, lb, XL);
    logits_simple<<<NODES, 256, 0, stream>>>(X, K, rW, rb, XL, nf, fill, att, eW, wbuf);
    out_simple<<<NODES, 256, 0, stream>>>(X, K, sW, bias, XL, wbuf, g, b);
    K = 256;
  }
  pool_kernel<<<BB, 256, 0, stream>>>(X, (float*)d_out);
}

// Round 7
// 1748.668 us; speedup vs baseline: 10.3466x; 10.3466x over previous
//
#include <hip/hip_runtime.h>
#include <hip/hip_bf16.h>
#include <math.h>

#define NODES 73728   // B*T*N = 128*64*9
#define BB    128
#define TT    64
#define NN    9
#define LDX   256
#define E_REAL 203648.0f
#define NARR  33

typedef __hip_bfloat16 bf16;

__device__ __forceinline__ float bfdec(unsigned short u) {
  return __uint_as_float(((unsigned)u) << 16);
}
__device__ __forceinline__ unsigned short f2bf(float x) {
  bf16 h = __float2bfloat16(x);
  return *(unsigned short*)&h;
}
__device__ __forceinline__ float4 ldbf4(const bf16* p) {  // 8B-aligned
  ushort4 u = *(const ushort4*)p;
  float4 f;
  f.x = bfdec(u.x); f.y = bfdec(u.y); f.z = bfdec(u.z); f.w = bfdec(u.w);
  return f;
}

// ---------------- dtype detector ----------------
__global__ __launch_bounds__(256) void detect_kernel(const unsigned short* __restrict__ raw,
                                                     float* __restrict__ flag) {
  __shared__ float sm[256];
  float mx = 0.f;
  for (int i = threadIdx.x; i < 2048; i += 256) mx = fmaxf(mx, fabsf(bfdec(raw[2 * i])));
  sm[threadIdx.x] = mx;
  __syncthreads();
  for (int s = 128; s > 0; s >>= 1) {
    if (threadIdx.x < s) sm[threadIdx.x] = fmaxf(sm[threadIdx.x], sm[threadIdx.x + s]);
    __syncthreads();
  }
  if (threadIdx.x == 0) flag[0] = (sm[0] > 1000.f) ? 1.f : 0.f;
}

// ---------------- convert all inputs to fp32 params region ----------------
struct CvtArgs { const void* src[NARR]; int size[NARR]; int off[NARR]; };

__global__ __launch_bounds__(256) void convert_kernel(CvtArgs a, const float* __restrict__ flag,
                                                      float* __restrict__ dst) {
  int i = blockIdx.y;
  int sz = a.size[i];
  bool isf32 = flag[0] > 0.5f;
  const float* sf = (const float*)a.src[i];
  const unsigned short* sh = (const unsigned short*)a.src[i];
  float* d = dst + a.off[i];
  for (int j = blockIdx.x * 256 + threadIdx.x; j < sz; j += gridDim.x * 256)
    d[j] = isf32 ? sf[j] : bfdec(sh[j]);
}

// ---------------- encoder ----------------
__global__ __launch_bounds__(128) void encoder_simple(const float* __restrict__ nf,
    const float* __restrict__ encW, const float* __restrict__ encb, float* __restrict__ X) {
  int v = blockIdx.x, d = threadIdx.x, n = v % NN;
  float f[14];
#pragma unroll
  for (int i = 0; i < 10; i++) f[i] = nf[(size_t)v * 10 + i];
  f[10] = (n < 7) ? 1.f : 0.f;
  f[11] = (n == 7) ? 1.f : 0.f;
  f[12] = (n == 8) ? 1.f : 0.f;
  f[13] = fabsf((float)(n - 7));
  const float* w = &encW[((size_t)n * 128 + d) * 14];
  float s = encb[n * 128 + d];
#pragma unroll
  for (int i = 0; i < 14; i++) s = fmaf(f[i], w[i], s);
  X[(size_t)v * LDX + d] = s;
}

// ---------------- fill ----------------
__global__ __launch_bounds__(256) void fill_kernel(const float* __restrict__ nf,
                                                   float* __restrict__ fill) {
  __shared__ float sx[256], sy[256], sz[256];
  int tid = threadIdx.x;
  float ax = 0.f, ay = 0.f, az = 0.f;
  for (int p = tid; p < BB * NN; p += 256) {
    int b = p / NN, n = p - b * NN;
    size_t late  = (((size_t)b * TT + (TT - 1)) * NN + n) * 10;
    size_t early = (((size_t)b * TT) * NN + n) * 10;
    ax += nf[late + 0] - nf[early + 0];
    ay += nf[late + 1] - nf[early + 1];
    az += nf[late + 2] - nf[early + 2];
  }
  sx[tid] = ax; sy[tid] = ay; sz[tid] = az;
  __syncthreads();
  for (int s = 128; s > 0; s >>= 1) {
    if (tid < s) { sx[tid] += sx[tid + s]; sy[tid] += sy[tid + s]; sz[tid] += sz[tid + s]; }
    __syncthreads();
  }
  if (tid == 0) { fill[0] = sx[0] / E_REAL; fill[1] = sy[0] / E_REAL; fill[2] = sz[0] / E_REAL; }
}

// ================= tiled GEMM core: 64 rows x 256 cols per block, 4x16 micro-tile =================
#define GEMM_BODY(SRC_X, WPTR)                                                          \
  int tid = threadIdx.x;                                                                \
  int row0 = blockIdx.x * 64;                                                           \
  int lm = tid >> 2, lk = (tid & 3) << 2;                                               \
  int r0 = (tid & 15) << 2, cg = (tid >> 4) << 4;                                       \
  float acc[4][16] = {};                                                                \
  for (int k0 = 0; k0 < K; k0 += 16) {                                                  \
    float4 av = *(const float4*)&SRC_X[(size_t)(row0 + lm) * LDX + k0 + lk];            \
    As[lk + 0][lm] = av.x; As[lk + 1][lm] = av.y;                                       \
    As[lk + 2][lm] = av.z; As[lk + 3][lm] = av.w;                                       \
    _Pragma("unroll")                                                                   \
    for (int p = 0; p < 4; p++) {                                                       \
      int c = p * 64 + lm;                                                              \
      float4 bv = *(const float4*)&WPTR[(size_t)c * K + k0 + lk];                       \
      Bs[lk + 0][c] = bv.x; Bs[lk + 1][c] = bv.y;                                       \
      Bs[lk + 2][c] = bv.z; Bs[lk + 3][c] = bv.w;                                       \
    }                                                                                   \
    __syncthreads();                                                                    \
    _Pragma("unroll")                                                                   \
    for (int kk = 0; kk < 16; kk++) {                                                   \
      float4 a4 = *(const float4*)&As[kk][r0];                                          \
      float a[4] = { a4.x, a4.y, a4.z, a4.w };                                          \
      float b[16];                                                                      \
      _Pragma("unroll")                                                                 \
      for (int j = 0; j < 16; j += 4) {                                                 \
        float4 b4 = *(const float4*)&Bs[kk][cg + j];                                    \
        b[j] = b4.x; b[j + 1] = b4.y; b[j + 2] = b4.z; b[j + 3] = b4.w;                 \
      }                                                                                 \
      _Pragma("unroll")                                                                 \
      for (int i = 0; i < 4; i++)                                                       \
        _Pragma("unroll")                                                               \
        for (int j = 0; j < 16; j++) acc[i][j] = fmaf(a[i], b[j], acc[i][j]);           \
    }                                                                                   \
    __syncthreads();                                                                    \
  }

// ---------------- XL = X @ lW.T + lb -> bf16 ----------------
__global__ __launch_bounds__(256) void gemm_xl_kernel(const float* __restrict__ x, int K,
    const float* __restrict__ W, const float* __restrict__ bias, bf16* __restrict__ XL) {
  __shared__ float As[16][68];
  __shared__ float Bs[16][260];
  GEMM_BODY(x, W)
#pragma unroll
  for (int i = 0; i < 4; i++) {
    size_t r = row0 + r0 + i;
#pragma unroll
    for (int j = 0; j < 16; j += 4) {
      ushort4 pk;
      pk.x = f2bf(acc[i][j + 0] + bias[cg + j + 0]);
      pk.y = f2bf(acc[i][j + 1] + bias[cg + j + 1]);
      pk.z = f2bf(acc[i][j + 2] + bias[cg + j + 2]);
      pk.w = f2bf(acc[i][j + 3] + bias[cg + j + 3]);
      *(ushort4*)&XL[r * LDX + cg + j] = pk;
    }
  }
}

// ---------------- fused: XR GEMM (LDS, bf16) + edge logits + softmax -> wbuf[v][h][e] ----------------
__global__ __launch_bounds__(256) void logits_kernel(const float* __restrict__ x, int K,
    const float* __restrict__ rW, const float* __restrict__ rb,
    const bf16* __restrict__ XL, const float* __restrict__ nf, const float* __restrict__ fill,
    const float* __restrict__ att, const float* __restrict__ eW, float* __restrict__ wbuf) {
  __shared__ float As[16][68];
  __shared__ float Bs[16][260];
  __shared__ unsigned short xr_s[64][264];
  GEMM_BODY(x, rW)
#pragma unroll
  for (int i = 0; i < 4; i++)
#pragma unroll
    for (int j = 0; j < 16; j += 4) {
      ushort4 pk;
      pk.x = f2bf(acc[i][j + 0] + rb[cg + j + 0]);
      pk.y = f2bf(acc[i][j + 1] + rb[cg + j + 1]);
      pk.z = f2bf(acc[i][j + 2] + rb[cg + j + 2]);
      pk.w = f2bf(acc[i][j + 3] + rb[cg + j + 3]);
      *(ushort4*)&xr_s[r0 + i][cg + j] = pk;
    }
  __syncthreads();

  int wave = tid >> 6, lane = tid & 63;
  int cc = lane << 2;        // 4 channels/lane; 16 lanes = one head
  int h = lane >> 4;
  float attv[4], ew[4][3];
#pragma unroll
  for (int i = 0; i < 4; i++) {
    attv[i] = att[cc + i];
    ew[i][0] = eW[(cc + i) * 3 + 0];
    ew[i][1] = eW[(cc + i) * 3 + 1];
    ew[i][2] = eW[(cc + i) * 3 + 2];
  }
  float f0 = fill[0], f1 = fill[1], f2 = fill[2];
  for (int k = 0; k < 16; k++) {
    int v = row0 + wave * 16 + k;
    int n = v % NN;
    int t = (v / NN) & 63;
    int srcs[4] = { v, (n > 0) ? v - 1 : v, (n < NN - 1) ? v + 1 : v, (t > 0) ? v - NN : v };
    bool valid[4] = { true, n > 0, n < NN - 1, t > 0 };
    float px = nf[(size_t)v * 10 + 0];
    float py = nf[(size_t)v * 10 + 1];
    float pz = nf[(size_t)v * 10 + 2];
    ushort4 xr4 = *(const ushort4*)&xr_s[wave * 16 + k][cc];
    float xr[4] = { bfdec(xr4.x), bfdec(xr4.y), bfdec(xr4.z), bfdec(xr4.w) };
    float logit[4];
#pragma unroll
    for (int e = 0; e < 4; e++) {
      int s = srcs[e];
      float a0, a1, a2;
      if (e == 0) { a0 = f0; a1 = f1; a2 = f2; }
      else {
        a0 = px - nf[(size_t)s * 10 + 0];
        a1 = py - nf[(size_t)s * 10 + 1];
        a2 = pz - nf[(size_t)s * 10 + 2];
      }
      float4 xl = ldbf4(&XL[(size_t)s * LDX + cc]);
      float xlv[4] = { xl.x, xl.y, xl.z, xl.w };
      float p = 0.f;
#pragma unroll
      for (int i = 0; i < 4; i++) {
        float em = fmaf(ew[i][0], a0, fmaf(ew[i][1], a1, ew[i][2] * a2));
        float mv = xlv[i] + xr[i] + em;
        mv = (mv > 0.f) ? mv : 0.2f * mv;   // leaky_relu 0.2
        p = fmaf(mv, attv[i], p);
      }
      p += __shfl_xor(p, 1); p += __shfl_xor(p, 2); p += __shfl_xor(p, 4); p += __shfl_xor(p, 8);
      logit[e] = valid[e] ? p : -1e30f;
    }
    float mx = fmaxf(fmaxf(logit[0], logit[1]), fmaxf(logit[2], logit[3]));
    float wv[4], wsum = 0.f;
#pragma unroll
    for (int e = 0; e < 4; e++) { wv[e] = __expf(logit[e] - mx); wsum += wv[e]; }
    float inv = 1.f / wsum;
    if ((lane & 15) == 0) {
      float4 w4 = { wv[0] * inv, wv[1] * inv, wv[2] * inv, wv[3] * inv };
      *(float4*)&wbuf[(size_t)v * 16 + h * 4] = w4;   // layout [v][h][e]
    }
  }
}

// ---------------- fused: XO = X@sW.T + bias + sum_e w*XL[src]; LN; SiLU; in-place ----------------
__global__ __launch_bounds__(256) void out_kernel(float* X, int K,
    const float* __restrict__ sW, const float* __restrict__ bias,
    const bf16* __restrict__ XL, const float* __restrict__ wbuf,
    const float* __restrict__ gamma, const float* __restrict__ beta) {
  __shared__ float As[16][68];
  __shared__ float Bs[16][260];
  __shared__ unsigned short xo_s[64][264];
  GEMM_BODY(X, sW)
#pragma unroll
  for (int i = 0; i < 4; i++)
#pragma unroll
    for (int j = 0; j < 16; j += 4) {
      ushort4 pk;
      pk.x = f2bf(acc[i][j + 0] + bias[cg + j + 0]);
      pk.y = f2bf(acc[i][j + 1] + bias[cg + j + 1]);
      pk.z = f2bf(acc[i][j + 2] + bias[cg + j + 2]);
      pk.w = f2bf(acc[i][j + 3] + bias[cg + j + 3]);
      *(ushort4*)&xo_s[r0 + i][cg + j] = pk;
    }
  __syncthreads();

  int wave = tid >> 6, lane = tid & 63;
  int cc = lane << 2;
  int h = lane >> 4;
  float gm[4], bt[4];
#pragma unroll
  for (int i = 0; i < 4; i++) { gm[i] = gamma[cc + i]; bt[i] = beta[cc + i]; }
  for (int k = 0; k < 16; k++) {
    int v = row0 + wave * 16 + k;
    int n = v % NN;
    int t = (v / NN) & 63;
    int srcs[4] = { v, (n > 0) ? v - 1 : v, (n < NN - 1) ? v + 1 : v, (t > 0) ? v - NN : v };
    float4 w4 = *(const float4*)&wbuf[(size_t)v * 16 + h * 4];
    float wv[4] = { w4.x, w4.y, w4.z, w4.w };   // invalid edges have weight exactly 0
    ushort4 xo4 = *(const ushort4*)&xo_s[wave * 16 + k][cc];
    float xv[4] = { bfdec(xo4.x), bfdec(xo4.y), bfdec(xo4.z), bfdec(xo4.w) };
#pragma unroll
    for (int e = 0; e < 4; e++) {
      float4 xl = ldbf4(&XL[(size_t)srcs[e] * LDX + cc]);
      xv[0] = fmaf(wv[e], xl.x, xv[0]);
      xv[1] = fmaf(wv[e], xl.y, xv[1]);
      xv[2] = fmaf(wv[e], xl.z, xv[2]);
      xv[3] = fmaf(wv[e], xl.w, xv[3]);
    }
    // LayerNorm over 256 channels (full-wave shuffle reduce)
    float s1 = xv[0] + xv[1] + xv[2] + xv[3];
#pragma unroll
    for (int off = 1; off < 64; off <<= 1) s1 += __shfl_xor(s1, off);
    float mu = s1 * (1.f / 256.f);
    float s2 = 0.f;
#pragma unroll
    for (int i = 0; i < 4; i++) { float d = xv[i] - mu; s2 = fmaf(d, d, s2); }
#pragma unroll
    for (int off = 1; off < 64; off <<= 1) s2 += __shfl_xor(s2, off);
    float rs = rsqrtf(s2 * (1.f / 256.f) + 1e-5f);
    float4 o;
    float* op = &o.x;
#pragma unroll
    for (int i = 0; i < 4; i++) {
      float y = (xv[i] - mu) * rs * gm[i] + bt[i];
      op[i] = y * (1.f / (1.f + __expf(-y)));   // SiLU
    }
    *(float4*)&X[(size_t)v * LDX + cc] = o;
  }
}

// ---------------- mean over 576 positions -> (B,256) fp32 ----------------
__global__ __launch_bounds__(256) void pool_kernel(const float* __restrict__ X,
                                                   float* __restrict__ out) {
  int b = blockIdx.x, c = threadIdx.x;
  const float* p = &X[(size_t)b * 576 * LDX + c];
  float s = 0.f;
  for (int i = 0; i < 576; i++) s += p[(size_t)i * LDX];
  out[b * 256 + c] = s * (1.f / 576.f);
}

extern "C" void kernel_launch(void* const* d_in, const int* in_sizes, int n_in,
                              void* d_out, int out_size, void* d_ws, size_t ws_size,
                              hipStream_t stream) {
  static const int kSize[NARR] = {
    737280, 16128, 1152,
    32768, 256, 32768, 256, 256, 768, 32768, 256, 256, 256,   // layer 0 (K=128)
    65536, 256, 65536, 256, 256, 768, 65536, 256, 256, 256,   // layer 1 (K=256)
    65536, 256, 65536, 256, 256, 768, 65536, 256, 256, 256    // layer 2 (K=256)
  };
  if (n_in != NARR || out_size != BB * 256) return;
  for (int i = 0; i < NARR; i++) if (in_sizes[i] != kSize[i]) return;

  CvtArgs ca;
  int off = 0;
  for (int i = 0; i < NARR; i++) { ca.src[i] = d_in[i]; ca.size[i] = kSize[i]; ca.off[i] = off; off += kSize[i]; }
  const int PRM_ELEMS = off;   // 1,252,992

  const size_t OFF_FLAG = 0;
  const size_t OFF_FILL = 16;
  const size_t OFF_PRM  = 256;
  const size_t OFF_WB   = OFF_PRM + (size_t)PRM_ELEMS * 4;
  const size_t OFF_XL   = OFF_WB + (size_t)NODES * 16 * 4;
  const size_t OFF_X    = OFF_XL + (size_t)NODES * LDX * 2;    // XL bf16
  const size_t NEED     = OFF_X + (size_t)NODES * LDX * 4;     // ~117.3 MiB (proven fit)
  if (ws_size < NEED) return;

  char* ws = (char*)d_ws;
  float* flag = (float*)(ws + OFF_FLAG);
  float* fill = (float*)(ws + OFF_FILL);
  float* prm  = (float*)(ws + OFF_PRM);
  float* wbuf = (float*)(ws + OFF_WB);
  bf16*  XL   = (bf16*)(ws + OFF_XL);
  float* X    = (float*)(ws + OFF_X);

  detect_kernel<<<1, 256, 0, stream>>>((const unsigned short*)d_in[0], flag);
  convert_kernel<<<dim3(360, NARR), 256, 0, stream>>>(ca, flag, prm);

  const float* nf   = prm + ca.off[0];
  const float* encW = prm + ca.off[1];
  const float* encb = prm + ca.off[2];

  encoder_simple<<<NODES, 128, 0, stream>>>(nf, encW, encb, X);
  fill_kernel<<<1, 256, 0, stream>>>(nf, fill);

  int K = 128;
  for (int L = 0; L < 3; L++) {
    const float* lW   = prm + ca.off[3 + L * 10 + 0];
    const float* lb   = prm + ca.off[3 + L * 10 + 1];
    const float* rW   = prm + ca.off[3 + L * 10 + 2];
    const float* rb   = prm + ca.off[3 + L * 10 + 3];
    const float* att  = prm + ca.off[3 + L * 10 + 4];
    const float* eW   = prm + ca.off[3 + L * 10 + 5];
    const float* sW   = prm + ca.off[3 + L * 10 + 6];
    const float* bias = prm + ca.off[3 + L * 10 + 7];
    const float* g    = prm + ca.off[3 + L * 10 + 8];
    const float* b    = prm + ca.off[3 + L * 10 + 9];
    gemm_xl_kernel<<<NODES / 64, 256, 0, stream>>>(X, K, lW, lb, XL);
    logits_kernel<<<NODES / 64, 256, 0, stream>>>(X, K, rW, rb, XL, nf, fill, att, eW, wbuf);
    out_kernel<<<NODES / 64, 256, 0, stream>>>(X, K, sW, bias, XL, wbuf, g, b);
    K = 256;
  }
  pool_kernel<<<BB, 256, 0, stream>>>(X, (float*)d_out);
}

// Round 8
// 770.828 us; speedup vs baseline: 23.4719x; 2.2686x over previous
//
#include <hip/hip_runtime.h>
#include <hip/hip_bf16.h>
#include <math.h>

#define NODES 73728   // B*T*N = 128*64*9
#define BB    128
#define TT    64
#define NN    9
#define LDX   256
#define E_REAL 203648.0f
#define NARR  33

typedef __hip_bfloat16 bf16;
typedef _Float16 half8 __attribute__((ext_vector_type(8)));
typedef float f32x4 __attribute__((ext_vector_type(4)));

__device__ __forceinline__ float bfdec(unsigned short u) {
  return __uint_as_float(((unsigned)u) << 16);
}
__device__ __forceinline__ unsigned short f2bf(float x) {
  bf16 h = __float2bfloat16(x);
  return *(unsigned short*)&h;
}
__device__ __forceinline__ float4 ldbf4(const bf16* p) {  // 8B-aligned
  ushort4 u = *(const ushort4*)p;
  float4 f;
  f.x = bfdec(u.x); f.y = bfdec(u.y); f.z = bfdec(u.z); f.w = bfdec(u.w);
  return f;
}
// load 8 fp32, convert to f16, store 16B to LDS
__device__ __forceinline__ void cvt8h(const float* __restrict__ src, _Float16* dst) {
  float4 f0 = *(const float4*)src;
  float4 f1 = *(const float4*)(src + 4);
  half8 h;
  h[0] = (_Float16)f0.x; h[1] = (_Float16)f0.y; h[2] = (_Float16)f0.z; h[3] = (_Float16)f0.w;
  h[4] = (_Float16)f1.x; h[5] = (_Float16)f1.y; h[6] = (_Float16)f1.z; h[7] = (_Float16)f1.w;
  *(half8*)dst = h;
}

// ---------------- dtype detector ----------------
__global__ __launch_bounds__(256) void detect_kernel(const unsigned short* __restrict__ raw,
                                                     float* __restrict__ flag) {
  __shared__ float sm[256];
  float mx = 0.f;
  for (int i = threadIdx.x; i < 2048; i += 256) mx = fmaxf(mx, fabsf(bfdec(raw[2 * i])));
  sm[threadIdx.x] = mx;
  __syncthreads();
  for (int s = 128; s > 0; s >>= 1) {
    if (threadIdx.x < s) sm[threadIdx.x] = fmaxf(sm[threadIdx.x], sm[threadIdx.x + s]);
    __syncthreads();
  }
  if (threadIdx.x == 0) flag[0] = (sm[0] > 1000.f) ? 1.f : 0.f;
}

// ---------------- convert all inputs to fp32 params region ----------------
struct CvtArgs { const void* src[NARR]; int size[NARR]; int off[NARR]; };

__global__ __launch_bounds__(256) void convert_kernel(CvtArgs a, const float* __restrict__ flag,
                                                      float* __restrict__ dst) {
  int i = blockIdx.y;
  int sz = a.size[i];
  bool isf32 = flag[0] > 0.5f;
  const float* sf = (const float*)a.src[i];
  const unsigned short* sh = (const unsigned short*)a.src[i];
  float* d = dst + a.off[i];
  for (int j = blockIdx.x * 256 + threadIdx.x; j < sz; j += gridDim.x * 256)
    d[j] = isf32 ? sf[j] : bfdec(sh[j]);
}

// ---------------- encoder ----------------
__global__ __launch_bounds__(128) void encoder_simple(const float* __restrict__ nf,
    const float* __restrict__ encW, const float* __restrict__ encb, float* __restrict__ X) {
  int v = blockIdx.x, d = threadIdx.x, n = v % NN;
  float f[14];
#pragma unroll
  for (int i = 0; i < 10; i++) f[i] = nf[(size_t)v * 10 + i];
  f[10] = (n < 7) ? 1.f : 0.f;
  f[11] = (n == 7) ? 1.f : 0.f;
  f[12] = (n == 8) ? 1.f : 0.f;
  f[13] = fabsf((float)(n - 7));
  const float* w = &encW[((size_t)n * 128 + d) * 14];
  float s = encb[n * 128 + d];
#pragma unroll
  for (int i = 0; i < 14; i++) s = fmaf(f[i], w[i], s);
  X[(size_t)v * LDX + d] = s;
}

// ---------------- fill ----------------
__global__ __launch_bounds__(256) void fill_kernel(const float* __restrict__ nf,
                                                   float* __restrict__ fill) {
  __shared__ float sx[256], sy[256], sz[256];
  int tid = threadIdx.x;
  float ax = 0.f, ay = 0.f, az = 0.f;
  for (int p = tid; p < BB * NN; p += 256) {
    int b = p / NN, n = p - b * NN;
    size_t late  = (((size_t)b * TT + (TT - 1)) * NN + n) * 10;
    size_t early = (((size_t)b * TT) * NN + n) * 10;
    ax += nf[late + 0] - nf[early + 0];
    ay += nf[late + 1] - nf[early + 1];
    az += nf[late + 2] - nf[early + 2];
  }
  sx[tid] = ax; sy[tid] = ay; sz[tid] = az;
  __syncthreads();
  for (int s = 128; s > 0; s >>= 1) {
    if (tid < s) { sx[tid] += sx[tid + s]; sy[tid] += sy[tid + s]; sz[tid] += sz[tid + s]; }
    __syncthreads();
  }
  if (tid == 0) { fill[0] = sx[0] / E_REAL; fill[1] = sy[0] / E_REAL; fill[2] = sz[0] / E_REAL; }
}

// ================= MFMA GEMM core: 64 rows x 256 cols per block =================
// C[row0+r, c] = sum_k X[row0+r, k] * W[c, k]   (fp32 in, f16 MFMA, fp32 acc)
// Per wave: 4 row-tiles x 4 col-tiles (cols wv*64..+63) of 16x16, K-step 32.
// LDS tiles padded to stride 40 (2-way bank aliasing only).
#define LDA 40
struct GemmSh { _Float16 A[64 * LDA]; _Float16 B[256 * LDA]; };

__device__ __forceinline__ void mfma_gemm(const float* __restrict__ x,
    const float* __restrict__ W, int K, int row0, int tid,
    _Float16* shA, _Float16* shB, f32x4 (&acc)[4][4]) {
  int lane = tid & 63, wv = tid >> 6;
  int quad = lane >> 4, mrow = lane & 15;
  int ar = tid >> 2, ak = (tid & 3) << 3;      // A stage: row, k-chunk
  for (int k0 = 0; k0 < K; k0 += 32) {
    cvt8h(&x[(size_t)(row0 + ar) * LDX + k0 + ak], &shA[ar * LDA + ak]);
#pragma unroll
    for (int j = 0; j < 4; j++)
      cvt8h(&W[(size_t)tid * K + k0 + (j << 3)], &shB[tid * LDA + (j << 3)]);
    __syncthreads();
    half8 af[4], bfr[4];
#pragma unroll
    for (int rt = 0; rt < 4; rt++)
      af[rt] = *(const half8*)&shA[(rt * 16 + mrow) * LDA + quad * 8];
#pragma unroll
    for (int ct = 0; ct < 4; ct++)
      bfr[ct] = *(const half8*)&shB[(wv * 64 + ct * 16 + mrow) * LDA + quad * 8];
#pragma unroll
    for (int rt = 0; rt < 4; rt++)
#pragma unroll
      for (int ct = 0; ct < 4; ct++)
        acc[rt][ct] = __builtin_amdgcn_mfma_f32_16x16x32_f16(af[rt], bfr[ct], acc[rt][ct], 0, 0, 0);
    __syncthreads();
  }
}

// write acc (+bias) into epilogue LDS buffer as bf16.  C/D map: col=lane&15, row=quad*4+reg
#define ACC_TO_EPI(EPI, BIASPTR)                                                \
  {                                                                             \
    int lane = tid & 63, wv = tid >> 6, quad = lane >> 4, mrow = lane & 15;     \
    _Pragma("unroll")                                                           \
    for (int rt = 0; rt < 4; rt++)                                              \
      _Pragma("unroll")                                                         \
      for (int ct = 0; ct < 4; ct++) {                                          \
        int col = wv * 64 + ct * 16 + mrow;                                     \
        float bs = BIASPTR[col];                                                \
        _Pragma("unroll")                                                       \
        for (int r = 0; r < 4; r++)                                             \
          EPI[rt * 16 + quad * 4 + r][col] = f2bf(acc[rt][ct][r] + bs);         \
      }                                                                         \
  }                                                                             \
  __syncthreads();

// ---------------- XL = X @ lW.T + lb -> bf16 ----------------
__global__ __launch_bounds__(256) void gemm_xl_kernel(const float* __restrict__ x, int K,
    const float* __restrict__ W, const float* __restrict__ bias, bf16* __restrict__ XL) {
  __shared__ union { GemmSh st; unsigned short epi[64][264]; } sh;
  int tid = threadIdx.x;
  int row0 = blockIdx.x * 64;
  f32x4 acc[4][4] = {};
  mfma_gemm(x, W, K, row0, tid, sh.st.A, sh.st.B, acc);
  ACC_TO_EPI(sh.epi, bias)
  int r = tid >> 2;
#pragma unroll
  for (int j = 0; j < 16; j++) {
    int c0 = (((tid & 3) << 4) + j) << 2;
    *(ushort4*)&XL[(size_t)(row0 + r) * LDX + c0] = *(const ushort4*)&sh.epi[r][c0];
  }
}

// ---------------- fused: XR GEMM + edge logits + softmax -> wbuf[v][h][e] ----------------
__global__ __launch_bounds__(256) void logits_kernel(const float* __restrict__ x, int K,
    const float* __restrict__ rW, const float* __restrict__ rb,
    const bf16* __restrict__ XL, const float* __restrict__ nf, const float* __restrict__ fill,
    const float* __restrict__ att, const float* __restrict__ eW, float* __restrict__ wbuf) {
  __shared__ union { GemmSh st; unsigned short epi[64][264]; } sh;
  int tid = threadIdx.x;
  int row0 = blockIdx.x * 64;
  f32x4 acc[4][4] = {};
  mfma_gemm(x, rW, K, row0, tid, sh.st.A, sh.st.B, acc);
  ACC_TO_EPI(sh.epi, rb)

  int wave = tid >> 6, lane = tid & 63;
  int cc = lane << 2;        // 4 channels/lane; 16 lanes = one head
  int h = lane >> 4;
  float attv[4], ew[4][3];
#pragma unroll
  for (int i = 0; i < 4; i++) {
    attv[i] = att[cc + i];
    ew[i][0] = eW[(cc + i) * 3 + 0];
    ew[i][1] = eW[(cc + i) * 3 + 1];
    ew[i][2] = eW[(cc + i) * 3 + 2];
  }
  float f0 = fill[0], f1 = fill[1], f2 = fill[2];
  for (int k = 0; k < 16; k++) {
    int v = row0 + wave * 16 + k;
    int n = v % NN;
    int t = (v / NN) & 63;
    int srcs[4] = { v, (n > 0) ? v - 1 : v, (n < NN - 1) ? v + 1 : v, (t > 0) ? v - NN : v };
    bool valid[4] = { true, n > 0, n < NN - 1, t > 0 };
    float px = nf[(size_t)v * 10 + 0];
    float py = nf[(size_t)v * 10 + 1];
    float pz = nf[(size_t)v * 10 + 2];
    ushort4 xr4 = *(const ushort4*)&sh.epi[wave * 16 + k][cc];
    float xr[4] = { bfdec(xr4.x), bfdec(xr4.y), bfdec(xr4.z), bfdec(xr4.w) };
    float logit[4];
#pragma unroll
    for (int e = 0; e < 4; e++) {
      int s = srcs[e];
      float a0, a1, a2;
      if (e == 0) { a0 = f0; a1 = f1; a2 = f2; }
      else {
        a0 = px - nf[(size_t)s * 10 + 0];
        a1 = py - nf[(size_t)s * 10 + 1];
        a2 = pz - nf[(size_t)s * 10 + 2];
      }
      float4 xl = ldbf4(&XL[(size_t)s * LDX + cc]);
      float xlv[4] = { xl.x, xl.y, xl.z, xl.w };
      float p = 0.f;
#pragma unroll
      for (int i = 0; i < 4; i++) {
        float em = fmaf(ew[i][0], a0, fmaf(ew[i][1], a1, ew[i][2] * a2));
        float mv = xlv[i] + xr[i] + em;
        mv = (mv > 0.f) ? mv : 0.2f * mv;   // leaky_relu 0.2
        p = fmaf(mv, attv[i], p);
      }
      p += __shfl_xor(p, 1); p += __shfl_xor(p, 2); p += __shfl_xor(p, 4); p += __shfl_xor(p, 8);
      logit[e] = valid[e] ? p : -1e30f;
    }
    float mx = fmaxf(fmaxf(logit[0], logit[1]), fmaxf(logit[2], logit[3]));
    float wv4[4], wsum = 0.f;
#pragma unroll
    for (int e = 0; e < 4; e++) { wv4[e] = __expf(logit[e] - mx); wsum += wv4[e]; }
    float inv = 1.f / wsum;
    if ((lane & 15) == 0) {
      float4 w4 = { wv4[0] * inv, wv4[1] * inv, wv4[2] * inv, wv4[3] * inv };
      *(float4*)&wbuf[(size_t)v * 16 + h * 4] = w4;   // layout [v][h][e]
    }
  }
}

// ---------------- fused: XO = X@sW.T + bias + sum_e w*XL[src]; LN; SiLU; in-place ----------------
__global__ __launch_bounds__(256) void out_kernel(float* X, int K,
    const float* __restrict__ sW, const float* __restrict__ bias,
    const bf16* __restrict__ XL, const float* __restrict__ wbuf,
    const float* __restrict__ gamma, const float* __restrict__ beta) {
  __shared__ union { GemmSh st; unsigned short epi[64][264]; } sh;
  int tid = threadIdx.x;
  int row0 = blockIdx.x * 64;
  f32x4 acc[4][4] = {};
  mfma_gemm(X, sW, K, row0, tid, sh.st.A, sh.st.B, acc);
  ACC_TO_EPI(sh.epi, bias)

  int wave = tid >> 6, lane = tid & 63;
  int cc = lane << 2;
  int h = lane >> 4;
  float gm[4], bt[4];
#pragma unroll
  for (int i = 0; i < 4; i++) { gm[i] = gamma[cc + i]; bt[i] = beta[cc + i]; }
  for (int k = 0; k < 16; k++) {
    int v = row0 + wave * 16 + k;
    int n = v % NN;
    int t = (v / NN) & 63;
    int srcs[4] = { v, (n > 0) ? v - 1 : v, (n < NN - 1) ? v + 1 : v, (t > 0) ? v - NN : v };
    float4 w4 = *(const float4*)&wbuf[(size_t)v * 16 + h * 4];
    float wv4[4] = { w4.x, w4.y, w4.z, w4.w };   // invalid edges have weight exactly 0
    ushort4 xo4 = *(const ushort4*)&sh.epi[wave * 16 + k][cc];
    float xv[4] = { bfdec(xo4.x), bfdec(xo4.y), bfdec(xo4.z), bfdec(xo4.w) };
#pragma unroll
    for (int e = 0; e < 4; e++) {
      float4 xl = ldbf4(&XL[(size_t)srcs[e] * LDX + cc]);
      xv[0] = fmaf(wv4[e], xl.x, xv[0]);
      xv[1] = fmaf(wv4[e], xl.y, xv[1]);
      xv[2] = fmaf(wv4[e], xl.z, xv[2]);
      xv[3] = fmaf(wv4[e], xl.w, xv[3]);
    }
    // LayerNorm over 256 channels (full-wave shuffle reduce)
    float s1 = xv[0] + xv[1] + xv[2] + xv[3];
#pragma unroll
    for (int off = 1; off < 64; off <<= 1) s1 += __shfl_xor(s1, off);
    float mu = s1 * (1.f / 256.f);
    float s2 = 0.f;
#pragma unroll
    for (int i = 0; i < 4; i++) { float d = xv[i] - mu; s2 = fmaf(d, d, s2); }
#pragma unroll
    for (int off = 1; off < 64; off <<= 1) s2 += __shfl_xor(s2, off);
    float rs = rsqrtf(s2 * (1.f / 256.f) + 1e-5f);
    float4 o;
    float* op = &o.x;
#pragma unroll
    for (int i = 0; i < 4; i++) {
      float y = (xv[i] - mu) * rs * gm[i] + bt[i];
      op[i] = y * (1.f / (1.f + __expf(-y)));   // SiLU
    }
    *(float4*)&X[(size_t)v * LDX + cc] = o;
  }
}

// ---------------- mean over 576 positions -> (B,256) fp32 ----------------
__global__ __launch_bounds__(256) void pool_kernel(const float* __restrict__ X,
                                                   float* __restrict__ out) {
  int b = blockIdx.x, c = threadIdx.x;
  const float* p = &X[(size_t)b * 576 * LDX + c];
  float s = 0.f;
  for (int i = 0; i < 576; i++) s += p[(size_t)i * LDX];
  out[b * 256 + c] = s * (1.f / 576.f);
}

extern "C" void kernel_launch(void* const* d_in, const int* in_sizes, int n_in,
                              void* d_out, int out_size, void* d_ws, size_t ws_size,
                              hipStream_t stream) {
  static const int kSize[NARR] = {
    737280, 16128, 1152,
    32768, 256, 32768, 256, 256, 768, 32768, 256, 256, 256,   // layer 0 (K=128)
    65536, 256, 65536, 256, 256, 768, 65536, 256, 256, 256,   // layer 1 (K=256)
    65536, 256, 65536, 256, 256, 768, 65536, 256, 256, 256    // layer 2 (K=256)
  };
  if (n_in != NARR || out_size != BB * 256) return;
  for (int i = 0; i < NARR; i++) if (in_sizes[i] != kSize[i]) return;

  CvtArgs ca;
  int off = 0;
  for (int i = 0; i < NARR; i++) { ca.src[i] = d_in[i]; ca.size[i] = kSize[i]; ca.off[i] = off; off += kSize[i]; }
  const int PRM_ELEMS = off;   // 1,252,992

  const size_t OFF_FLAG = 0;
  const size_t OFF_FILL = 16;
  const size_t OFF_PRM  = 256;
  const size_t OFF_WB   = OFF_PRM + (size_t)PRM_ELEMS * 4;
  const size_t OFF_XL   = OFF_WB + (size_t)NODES * 16 * 4;
  const size_t OFF_X    = OFF_XL + (size_t)NODES * LDX * 2;    // XL bf16
  const size_t NEED     = OFF_X + (size_t)NODES * LDX * 4;     // ~117.3 MiB (proven fit)
  if (ws_size < NEED) return;

  char* ws = (char*)d_ws;
  float* flag = (float*)(ws + OFF_FLAG);
  float* fill = (float*)(ws + OFF_FILL);
  float* prm  = (float*)(ws + OFF_PRM);
  float* wbuf = (float*)(ws + OFF_WB);
  bf16*  XL   = (bf16*)(ws + OFF_XL);
  float* X    = (float*)(ws + OFF_X);

  detect_kernel<<<1, 256, 0, stream>>>((const unsigned short*)d_in[0], flag);
  convert_kernel<<<dim3(360, NARR), 256, 0, stream>>>(ca, flag, prm);

  const float* nf   = prm + ca.off[0];
  const float* encW = prm + ca.off[1];
  const float* encb = prm + ca.off[2];

  encoder_simple<<<NODES, 128, 0, stream>>>(nf, encW, encb, X);
  fill_kernel<<<1, 256, 0, stream>>>(nf, fill);

  int K = 128;
  for (int L = 0; L < 3; L++) {
    const float* lW   = prm + ca.off[3 + L * 10 + 0];
    const float* lb   = prm + ca.off[3 + L * 10 + 1];
    const float* rW   = prm + ca.off[3 + L * 10 + 2];
    const float* rb   = prm + ca.off[3 + L * 10 + 3];
    const float* att  = prm + ca.off[3 + L * 10 + 4];
    const float* eW   = prm + ca.off[3 + L * 10 + 5];
    const float* sW   = prm + ca.off[3 + L * 10 + 6];
    const float* bias = prm + ca.off[3 + L * 10 + 7];
    const float* g    = prm + ca.off[3 + L * 10 + 8];
    const float* b    = prm + ca.off[3 + L * 10 + 9];
    gemm_xl_kernel<<<NODES / 64, 256, 0, stream>>>(X, K, lW, lb, XL);
    logits_kernel<<<NODES / 64, 256, 0, stream>>>(X, K, rW, rb, XL, nf, fill, att, eW, wbuf);
    out_kernel<<<NODES / 64, 256, 0, stream>>>(X, K, sW, bias, XL, wbuf, g, b);
    K = 256;
  }
  pool_kernel<<<BB, 256, 0, stream>>>(X, (float*)d_out);
}

// Round 9
// 628.806 us; speedup vs baseline: 28.7733x; 1.2259x over previous
//
#include <hip/hip_runtime.h>
#include <hip/hip_bf16.h>
#include <math.h>

#define NODES 73728   // B*T*N = 128*64*9
#define BB    128
#define TT    64
#define NN    9
#define LDX   256
#define E_REAL 203648.0f
#define NARR  33

typedef __hip_bfloat16 bf16;
typedef _Float16 half8 __attribute__((ext_vector_type(8)));
typedef _Float16 half4 __attribute__((ext_vector_type(4)));
typedef float f32x4 __attribute__((ext_vector_type(4)));

__device__ __forceinline__ float bfdec(unsigned short u) {
  return __uint_as_float(((unsigned)u) << 16);
}
__device__ __forceinline__ unsigned short f2bf(float x) {
  bf16 h = __float2bfloat16(x);
  return *(unsigned short*)&h;
}
__device__ __forceinline__ float4 ldbf4(const bf16* p) {  // 8B-aligned
  ushort4 u = *(const ushort4*)p;
  float4 f;
  f.x = bfdec(u.x); f.y = bfdec(u.y); f.z = bfdec(u.z); f.w = bfdec(u.w);
  return f;
}

// ---------------- dtype detector ----------------
__global__ __launch_bounds__(256) void detect_kernel(const unsigned short* __restrict__ raw,
                                                     float* __restrict__ flag) {
  __shared__ float sm[256];
  float mx = 0.f;
  for (int i = threadIdx.x; i < 2048; i += 256) mx = fmaxf(mx, fabsf(bfdec(raw[2 * i])));
  sm[threadIdx.x] = mx;
  __syncthreads();
  for (int s = 128; s > 0; s >>= 1) {
    if (threadIdx.x < s) sm[threadIdx.x] = fmaxf(sm[threadIdx.x], sm[threadIdx.x + s]);
    __syncthreads();
  }
  if (threadIdx.x == 0) flag[0] = (sm[0] > 1000.f) ? 1.f : 0.f;
}

// ---------------- convert all inputs to fp32 params region ----------------
struct CvtArgs { const void* src[NARR]; int size[NARR]; int off[NARR]; };

__global__ __launch_bounds__(256) void convert_kernel(CvtArgs a, const float* __restrict__ flag,
                                                      float* __restrict__ dst) {
  int i = blockIdx.y;
  int sz = a.size[i];
  bool isf32 = flag[0] > 0.5f;
  const float* sf = (const float*)a.src[i];
  const unsigned short* sh = (const unsigned short*)a.src[i];
  float* d = dst + a.off[i];
  for (int j = blockIdx.x * 256 + threadIdx.x; j < sz; j += gridDim.x * 256)
    d[j] = isf32 ? sf[j] : bfdec(sh[j]);
}

// ---------------- f16 shadow of the whole param region (weights read from here) ----------------
__global__ __launch_bounds__(256) void tohalf_kernel(const float* __restrict__ prm,
                                                     _Float16* __restrict__ dst, int n) {
  int i = blockIdx.x * 256 + threadIdx.x;
  if (i < n) dst[i] = (_Float16)prm[i];
}

// ---------------- encoder -> X f16 ----------------
__global__ __launch_bounds__(128) void encoder_simple(const float* __restrict__ nf,
    const float* __restrict__ encW, const float* __restrict__ encb, _Float16* __restrict__ Xh) {
  int v = blockIdx.x, d = threadIdx.x, n = v % NN;
  float f[14];
#pragma unroll
  for (int i = 0; i < 10; i++) f[i] = nf[(size_t)v * 10 + i];
  f[10] = (n < 7) ? 1.f : 0.f;
  f[11] = (n == 7) ? 1.f : 0.f;
  f[12] = (n == 8) ? 1.f : 0.f;
  f[13] = fabsf((float)(n - 7));
  const float* w = &encW[((size_t)n * 128 + d) * 14];
  float s = encb[n * 128 + d];
#pragma unroll
  for (int i = 0; i < 14; i++) s = fmaf(f[i], w[i], s);
  Xh[(size_t)v * LDX + d] = (_Float16)s;
}

// ---------------- fill ----------------
__global__ __launch_bounds__(256) void fill_kernel(const float* __restrict__ nf,
                                                   float* __restrict__ fill) {
  __shared__ float sx[256], sy[256], sz[256];
  int tid = threadIdx.x;
  float ax = 0.f, ay = 0.f, az = 0.f;
  for (int p = tid; p < BB * NN; p += 256) {
    int b = p / NN, n = p - b * NN;
    size_t late  = (((size_t)b * TT + (TT - 1)) * NN + n) * 10;
    size_t early = (((size_t)b * TT) * NN + n) * 10;
    ax += nf[late + 0] - nf[early + 0];
    ay += nf[late + 1] - nf[early + 1];
    az += nf[late + 2] - nf[early + 2];
  }
  sx[tid] = ax; sy[tid] = ay; sz[tid] = az;
  __syncthreads();
  for (int s = 128; s > 0; s >>= 1) {
    if (tid < s) { sx[tid] += sx[tid + s]; sy[tid] += sy[tid + s]; sz[tid] += sz[tid + s]; }
    __syncthreads();
  }
  if (tid == 0) { fill[0] = sx[0] / E_REAL; fill[1] = sy[0] / E_REAL; fill[2] = sz[0] / E_REAL; }
}

// ================= MFMA GEMM core: 64 rows x 256 cols per block, f16 operands =================
// C[row0+r, c] = sum_k Xh[row0+r, k] * Wh[c, k]   (f16 MFMA, fp32 acc)
// LDS tiles padded to stride 40 f16.
#define LDA 40
struct GemmSh { _Float16 A[64 * LDA]; _Float16 B[256 * LDA]; };

__device__ __forceinline__ void mfma_gemm(const _Float16* __restrict__ x,
    const _Float16* __restrict__ W, int K, int row0, int tid,
    _Float16* shA, _Float16* shB, f32x4 (&acc)[4][4]) {
  int lane = tid & 63, wv = tid >> 6;
  int quad = lane >> 4, mrow = lane & 15;
  int ar = tid >> 2, ak = (tid & 3) << 3;      // A stage: row, k-chunk
  for (int k0 = 0; k0 < K; k0 += 32) {
    *(half8*)&shA[ar * LDA + ak] = *(const half8*)&x[(size_t)(row0 + ar) * LDX + k0 + ak];
#pragma unroll
    for (int j = 0; j < 4; j++)
      *(half8*)&shB[tid * LDA + (j << 3)] = *(const half8*)&W[(size_t)tid * K + k0 + (j << 3)];
    __syncthreads();
    half8 af[4], bfr[4];
#pragma unroll
    for (int rt = 0; rt < 4; rt++)
      af[rt] = *(const half8*)&shA[(rt * 16 + mrow) * LDA + quad * 8];
#pragma unroll
    for (int ct = 0; ct < 4; ct++)
      bfr[ct] = *(const half8*)&shB[(wv * 64 + ct * 16 + mrow) * LDA + quad * 8];
#pragma unroll
    for (int rt = 0; rt < 4; rt++)
#pragma unroll
      for (int ct = 0; ct < 4; ct++)
        acc[rt][ct] = __builtin_amdgcn_mfma_f32_16x16x32_f16(af[rt], bfr[ct], acc[rt][ct], 0, 0, 0);
    __syncthreads();
  }
}

// write acc (+bias) into epilogue LDS buffer as bf16.  C/D map: col=lane&15, row=quad*4+reg
#define ACC_TO_EPI(EPI, BIASPTR)                                                \
  {                                                                             \
    int lane = tid & 63, wv = tid >> 6, quad = lane >> 4, mrow = lane & 15;     \
    _Pragma("unroll")                                                           \
    for (int rt = 0; rt < 4; rt++)                                              \
      _Pragma("unroll")                                                         \
      for (int ct = 0; ct < 4; ct++) {                                          \
        int col = wv * 64 + ct * 16 + mrow;                                     \
        float bs = BIASPTR[col];                                                \
        _Pragma("unroll")                                                       \
        for (int r = 0; r < 4; r++)                                             \
          EPI[rt * 16 + quad * 4 + r][col] = f2bf(acc[rt][ct][r] + bs);         \
      }                                                                         \
  }                                                                             \
  __syncthreads();

// ---------------- XL = X @ lW.T + lb -> bf16 ----------------
__global__ __launch_bounds__(256) void gemm_xl_kernel(const _Float16* __restrict__ x, int K,
    const _Float16* __restrict__ W, const float* __restrict__ bias, bf16* __restrict__ XL) {
  __shared__ union { GemmSh st; unsigned short epi[64][264]; } sh;
  int tid = threadIdx.x;
  int row0 = blockIdx.x * 64;
  f32x4 acc[4][4] = {};
  mfma_gemm(x, W, K, row0, tid, sh.st.A, sh.st.B, acc);
  ACC_TO_EPI(sh.epi, bias)
  int r = tid >> 2;
#pragma unroll
  for (int j = 0; j < 16; j++) {
    int c0 = (((tid & 3) << 4) + j) << 2;
    *(ushort4*)&XL[(size_t)(row0 + r) * LDX + c0] = *(const ushort4*)&sh.epi[r][c0];
  }
}

// ---------------- fused: XR GEMM + edge logits + softmax -> wbuf[v][h][e] ----------------
__global__ __launch_bounds__(256) void logits_kernel(const _Float16* __restrict__ x, int K,
    const _Float16* __restrict__ rW, const float* __restrict__ rb,
    const bf16* __restrict__ XL, const float* __restrict__ nf, const float* __restrict__ fill,
    const float* __restrict__ att, const float* __restrict__ eW, float* __restrict__ wbuf) {
  __shared__ union { GemmSh st; unsigned short epi[64][264]; } sh;
  int tid = threadIdx.x;
  int row0 = blockIdx.x * 64;
  f32x4 acc[4][4] = {};
  mfma_gemm(x, rW, K, row0, tid, sh.st.A, sh.st.B, acc);
  ACC_TO_EPI(sh.epi, rb)

  int wave = tid >> 6, lane = tid & 63;
  int cc = lane << 2;        // 4 channels/lane; 16 lanes = one head
  int h = lane >> 4;
  float attv[4], ew[4][3];
#pragma unroll
  for (int i = 0; i < 4; i++) {
    attv[i] = att[cc + i];
    ew[i][0] = eW[(cc + i) * 3 + 0];
    ew[i][1] = eW[(cc + i) * 3 + 1];
    ew[i][2] = eW[(cc + i) * 3 + 2];
  }
  float f0 = fill[0], f1 = fill[1], f2 = fill[2];
  for (int k = 0; k < 16; k++) {
    int v = row0 + wave * 16 + k;
    int n = v % NN;
    int t = (v / NN) & 63;
    int srcs[4] = { v, (n > 0) ? v - 1 : v, (n < NN - 1) ? v + 1 : v, (t > 0) ? v - NN : v };
    bool valid[4] = { true, n > 0, n < NN - 1, t > 0 };
    float px = nf[(size_t)v * 10 + 0];
    float py = nf[(size_t)v * 10 + 1];
    float pz = nf[(size_t)v * 10 + 2];
    ushort4 xr4 = *(const ushort4*)&sh.epi[wave * 16 + k][cc];
    float xr[4] = { bfdec(xr4.x), bfdec(xr4.y), bfdec(xr4.z), bfdec(xr4.w) };
    float logit[4];
#pragma unroll
    for (int e = 0; e < 4; e++) {
      int s = srcs[e];
      float a0, a1, a2;
      if (e == 0) { a0 = f0; a1 = f1; a2 = f2; }
      else {
        a0 = px - nf[(size_t)s * 10 + 0];
        a1 = py - nf[(size_t)s * 10 + 1];
        a2 = pz - nf[(size_t)s * 10 + 2];
      }
      float4 xl = ldbf4(&XL[(size_t)s * LDX + cc]);
      float xlv[4] = { xl.x, xl.y, xl.z, xl.w };
      float p = 0.f;
#pragma unroll
      for (int i = 0; i < 4; i++) {
        float em = fmaf(ew[i][0], a0, fmaf(ew[i][1], a1, ew[i][2] * a2));
        float mv = xlv[i] + xr[i] + em;
        mv = (mv > 0.f) ? mv : 0.2f * mv;   // leaky_relu 0.2
        p = fmaf(mv, attv[i], p);
      }
      p += __shfl_xor(p, 1); p += __shfl_xor(p, 2); p += __shfl_xor(p, 4); p += __shfl_xor(p, 8);
      logit[e] = valid[e] ? p : -1e30f;
    }
    float mx = fmaxf(fmaxf(logit[0], logit[1]), fmaxf(logit[2], logit[3]));
    float wv4[4], wsum = 0.f;
#pragma unroll
    for (int e = 0; e < 4; e++) { wv4[e] = __expf(logit[e] - mx); wsum += wv4[e]; }
    float inv = 1.f / wsum;
    if ((lane & 15) == 0) {
      float4 w4 = { wv4[0] * inv, wv4[1] * inv, wv4[2] * inv, wv4[3] * inv };
      *(float4*)&wbuf[(size_t)v * 16 + h * 4] = w4;   // layout [v][h][e]
    }
  }
}

// ---------------- fused: XO = X@sW.T + bias + sum_e w*XL[src]; LN; SiLU; X f16 in-place ----------------
__global__ __launch_bounds__(256) void out_kernel(_Float16* Xh, int K,
    const _Float16* __restrict__ sW, const float* __restrict__ bias,
    const bf16* __restrict__ XL, const float* __restrict__ wbuf,
    const float* __restrict__ gamma, const float* __restrict__ beta) {
  __shared__ union { GemmSh st; unsigned short epi[64][264]; } sh;
  int tid = threadIdx.x;
  int row0 = blockIdx.x * 64;
  f32x4 acc[4][4] = {};
  mfma_gemm(Xh, sW, K, row0, tid, sh.st.A, sh.st.B, acc);
  ACC_TO_EPI(sh.epi, bias)

  int wave = tid >> 6, lane = tid & 63;
  int cc = lane << 2;
  int h = lane >> 4;
  float gm[4], bt[4];
#pragma unroll
  for (int i = 0; i < 4; i++) { gm[i] = gamma[cc + i]; bt[i] = beta[cc + i]; }
  for (int k = 0; k < 16; k++) {
    int v = row0 + wave * 16 + k;
    int n = v % NN;
    int t = (v / NN) & 63;
    int srcs[4] = { v, (n > 0) ? v - 1 : v, (n < NN - 1) ? v + 1 : v, (t > 0) ? v - NN : v };
    float4 w4 = *(const float4*)&wbuf[(size_t)v * 16 + h * 4];
    float wv4[4] = { w4.x, w4.y, w4.z, w4.w };   // invalid edges have weight exactly 0
    ushort4 xo4 = *(const ushort4*)&sh.epi[wave * 16 + k][cc];
    float xv[4] = { bfdec(xo4.x), bfdec(xo4.y), bfdec(xo4.z), bfdec(xo4.w) };
#pragma unroll
    for (int e = 0; e < 4; e++) {
      float4 xl = ldbf4(&XL[(size_t)srcs[e] * LDX + cc]);
      xv[0] = fmaf(wv4[e], xl.x, xv[0]);
      xv[1] = fmaf(wv4[e], xl.y, xv[1]);
      xv[2] = fmaf(wv4[e], xl.z, xv[2]);
      xv[3] = fmaf(wv4[e], xl.w, xv[3]);
    }
    // LayerNorm over 256 channels (full-wave shuffle reduce)
    float s1 = xv[0] + xv[1] + xv[2] + xv[3];
#pragma unroll
    for (int off = 1; off < 64; off <<= 1) s1 += __shfl_xor(s1, off);
    float mu = s1 * (1.f / 256.f);
    float s2 = 0.f;
#pragma unroll
    for (int i = 0; i < 4; i++) { float d = xv[i] - mu; s2 = fmaf(d, d, s2); }
#pragma unroll
    for (int off = 1; off < 64; off <<= 1) s2 += __shfl_xor(s2, off);
    float rs = rsqrtf(s2 * (1.f / 256.f) + 1e-5f);
    half4 o;
#pragma unroll
    for (int i = 0; i < 4; i++) {
      float y = (xv[i] - mu) * rs * gm[i] + bt[i];
      o[i] = (_Float16)(y * (1.f / (1.f + __expf(-y))));   // SiLU
    }
    *(half4*)&Xh[(size_t)v * LDX + cc] = o;
  }
}

// ---------------- mean over 576 positions -> (B,256) fp32 ----------------
__global__ __launch_bounds__(256) void pool_kernel(const _Float16* __restrict__ Xh,
                                                   float* __restrict__ out) {
  int b = blockIdx.x, c = threadIdx.x;
  const _Float16* p = &Xh[(size_t)b * 576 * LDX + c];
  float s = 0.f;
  for (int i = 0; i < 576; i++) s += (float)p[(size_t)i * LDX];
  out[b * 256 + c] = s * (1.f / 576.f);
}

extern "C" void kernel_launch(void* const* d_in, const int* in_sizes, int n_in,
                              void* d_out, int out_size, void* d_ws, size_t ws_size,
                              hipStream_t stream) {
  static const int kSize[NARR] = {
    737280, 16128, 1152,
    32768, 256, 32768, 256, 256, 768, 32768, 256, 256, 256,   // layer 0 (K=128)
    65536, 256, 65536, 256, 256, 768, 65536, 256, 256, 256,   // layer 1 (K=256)
    65536, 256, 65536, 256, 256, 768, 65536, 256, 256, 256    // layer 2 (K=256)
  };
  if (n_in != NARR || out_size != BB * 256) return;
  for (int i = 0; i < NARR; i++) if (in_sizes[i] != kSize[i]) return;

  CvtArgs ca;
  int off = 0;
  for (int i = 0; i < NARR; i++) { ca.src[i] = d_in[i]; ca.size[i] = kSize[i]; ca.off[i] = off; off += kSize[i]; }
  const int PRM_ELEMS = off;   // 1,252,992

  const size_t OFF_FLAG = 0;
  const size_t OFF_FILL = 16;
  const size_t OFF_PRM  = 256;
  const size_t OFF_PRMH = OFF_PRM + (size_t)PRM_ELEMS * 4;     // f16 shadow
  const size_t OFF_WB   = OFF_PRMH + (size_t)PRM_ELEMS * 2;
  const size_t OFF_XL   = OFF_WB + (size_t)NODES * 16 * 4;
  const size_t OFF_XH   = OFF_XL + (size_t)NODES * LDX * 2;    // XL bf16
  const size_t NEED     = OFF_XH + (size_t)NODES * LDX * 2;    // ~88 MiB (under proven 117)
  if (ws_size < NEED) return;

  char* ws = (char*)d_ws;
  float*     flag = (float*)(ws + OFF_FLAG);
  float*     fill = (float*)(ws + OFF_FILL);
  float*     prm  = (float*)(ws + OFF_PRM);
  _Float16*  prmh = (_Float16*)(ws + OFF_PRMH);
  float*     wbuf = (float*)(ws + OFF_WB);
  bf16*      XL   = (bf16*)(ws + OFF_XL);
  _Float16*  Xh   = (_Float16*)(ws + OFF_XH);

  detect_kernel<<<1, 256, 0, stream>>>((const unsigned short*)d_in[0], flag);
  convert_kernel<<<dim3(360, NARR), 256, 0, stream>>>(ca, flag, prm);
  tohalf_kernel<<<(PRM_ELEMS + 255) / 256, 256, 0, stream>>>(prm, prmh, PRM_ELEMS);

  const float* nf   = prm + ca.off[0];
  const float* encW = prm + ca.off[1];
  const float* encb = prm + ca.off[2];

  encoder_simple<<<NODES, 128, 0, stream>>>(nf, encW, encb, Xh);
  fill_kernel<<<1, 256, 0, stream>>>(nf, fill);

  int K = 128;
  for (int L = 0; L < 3; L++) {
    const _Float16* lWh = prmh + ca.off[3 + L * 10 + 0];
    const float*    lb  = prm  + ca.off[3 + L * 10 + 1];
    const _Float16* rWh = prmh + ca.off[3 + L * 10 + 2];
    const float*    rb  = prm  + ca.off[3 + L * 10 + 3];
    const float*    att = prm  + ca.off[3 + L * 10 + 4];
    const float*    eW  = prm  + ca.off[3 + L * 10 + 5];
    const _Float16* sWh = prmh + ca.off[3 + L * 10 + 6];
    const float*    bias= prm  + ca.off[3 + L * 10 + 7];
    const float*    g   = prm  + ca.off[3 + L * 10 + 8];
    const float*    b   = prm  + ca.off[3 + L * 10 + 9];
    gemm_xl_kernel<<<NODES / 64, 256, 0, stream>>>(Xh, K, lWh, lb, XL);
    logits_kernel<<<NODES / 64, 256, 0, stream>>>(Xh, K, rWh, rb, XL, nf, fill, att, eW, wbuf);
    out_kernel<<<NODES / 64, 256, 0, stream>>>(Xh, K, sWh, bias, XL, wbuf, g, b);
    K = 256;
  }
  pool_kernel<<<BB, 256, 0, stream>>>(Xh, (float*)d_out);
}